// Round 2
// baseline (171.829 us; speedup 1.0000x reference)
//
#include <hip/hip_runtime.h>
#include <math.h>

#define NB 256
#define NH 10
#define NI 1152
#define NW 16
#define NS 8

// One block = 512 threads = 2 halves of 256; each half owns one b for a fixed h.
// Grid = 10 h * 128 b-pairs = 1280 blocks (h-major so co-scheduled blocks share W[h] in L2).
// Routing trick: logits are linear in u: b_i^{(r)} = u_i . (v^0+...+v^{r-1}) = u_i . vacc.

__global__ __launch_bounds__(512, 2)
void digitcaps_kernel(const float* __restrict__ x,
                      const float* __restrict__ Wc,
                      float* __restrict__ out)
{
    // u stored swizzled: [half][w*NI + (i ^ (2w))] -> <=2-way banks on all access patterns
    __shared__ float u_lds[2][NW * NI];   // 147456 B
    __shared__ float e_lds[2][NI];        // 9216 B
    __shared__ float redM[8];
    __shared__ float redE[8];
    __shared__ float red3[8][16];
    __shared__ float vacc_sh[2][16];

    const int tid  = threadIdx.x;
    const int half = tid >> 8;        // which b of the pair
    const int t    = tid & 255;
    const int w    = t & 15;          // out-capsule dim owned by this thread
    const int il   = t >> 4;          // i-lane 0..15
    const int lane = tid & 63;
    const int wid  = tid >> 6;        // wave 0..7 (waves 0-3 = half 0)

    const int blk = blockIdx.x;
    const int h   = blk >> 7;         // 0..9
    const int bg  = blk & 127;        // b-pair index
    const int b   = bg * 2 + half;

    const float* xb = x  + (size_t)b * (NI * NS);
    const float* Wh = Wc + (size_t)h * ((size_t)NI * NW * NS);

    float u_reg[72];   // u[w][i = k*16+il] for k=0..71

    #pragma unroll
    for (int k = 0; k < 72; ++k) {
        int i = k * 16 + il;
        const float4* xp = reinterpret_cast<const float4*>(xb + (size_t)i * NS);
        float4 x0 = xp[0], x1 = xp[1];                       // broadcast across 16 w-lanes
        const float4* wp = reinterpret_cast<const float4*>(Wh + ((size_t)i * NW + w) * NS);
        float4 w0 = wp[0], w1 = wp[1];                       // coalesced 32B/lane
        float a = w0.x*x0.x + w0.y*x0.y + w0.z*x0.z + w0.w*x0.w
                + w1.x*x1.x + w1.y*x1.y + w1.z*x1.z + w1.w*x1.w;
        u_reg[k] = a;
        u_lds[half][w * NI + (i ^ (2 * w))] = a;
    }
    if (tid < 32) vacc_sh[tid >> 4][tid & 15] = 0.0f;
    __syncthreads();

    for (int r = 0; r < 3; ++r) {
        if (r > 0) {
            // ---- phase 1: d_i = u_i . vacc  (i-owner threads: i = t + 256k) ----
            float vloc[16];
            #pragma unroll
            for (int q = 0; q < 16; ++q) vloc[q] = vacc_sh[half][q];
            float dk[5];
            float m = -3.4e38f;
            #pragma unroll
            for (int k = 0; k < 5; ++k) {
                int i = t + 256 * k;
                if (k < 4 || t < (NI - 1024)) {
                    float d = 0.0f;
                    #pragma unroll
                    for (int q = 0; q < 16; ++q)
                        d += u_lds[half][q * NI + (i ^ (2 * q))] * vloc[q];
                    dk[k] = d;
                    m = fmaxf(m, d);
                }
            }
            #pragma unroll
            for (int s = 1; s < 64; s <<= 1) m = fmaxf(m, __shfl_xor(m, s));
            if (lane == 0) redM[wid] = m;
            __syncthreads();
            float M = fmaxf(fmaxf(redM[half*4+0], redM[half*4+1]),
                            fmaxf(redM[half*4+2], redM[half*4+3]));
            // ---- phase 2: e_i = exp(d_i - M), E = sum ----
            float Es = 0.0f;
            #pragma unroll
            for (int k = 0; k < 5; ++k) {
                int i = t + 256 * k;
                if (k < 4 || t < (NI - 1024)) {
                    float e = __expf(dk[k] - M);
                    e_lds[half][i] = e;
                    Es += e;
                }
            }
            #pragma unroll
            for (int s = 1; s < 64; s <<= 1) Es += __shfl_xor(Es, s);
            if (lane == 0) redE[wid] = Es;
            __syncthreads();   // e_lds + redE visible
        }
        // ---- phase 3: s_w = (1/E) * sum_i e_i * u[w][i]  (u from registers) ----
        float acc = 0.0f;
        if (r == 0) {
            #pragma unroll
            for (int k = 0; k < 72; ++k) acc += u_reg[k];
        } else {
            #pragma unroll
            for (int k = 0; k < 72; ++k) acc += e_lds[half][k * 16 + il] * u_reg[k];
        }
        acc += __shfl_xor(acc, 16);
        acc += __shfl_xor(acc, 32);       // sum over the wave's 4 il-groups
        if (lane < 16) red3[wid][lane] = acc;
        __syncthreads();
        if (tid < 32) {                   // 16 threads per half finish s -> v
            int hh = tid >> 4, w2 = tid & 15;
            float s = red3[hh*4+0][w2] + red3[hh*4+1][w2]
                    + red3[hh*4+2][w2] + red3[hh*4+3][w2];
            float Eh = (r == 0) ? (float)NI
                     : (redE[hh*4+0] + redE[hh*4+1] + redE[hh*4+2] + redE[hh*4+3]);
            s /= Eh;
            float sq = s * s;
            #pragma unroll
            for (int st = 1; st < 16; st <<= 1) sq += __shfl_xor(sq, st);
            float f = sqrtf(sq) / (1.0f + sq);   // squash scale: ||s||/(1+||s||^2)
            float v = s * f;
            if (r < 2) vacc_sh[hh][w2] += v;
            else {
                int bb = bg * 2 + hh;
                out[((size_t)bb * NH + h) * NW + w2] = v;
            }
        }
        __syncthreads();
    }
}

extern "C" void kernel_launch(void* const* d_in, const int* in_sizes, int n_in,
                              void* d_out, int out_size, void* d_ws, size_t ws_size,
                              hipStream_t stream) {
    const float* x  = (const float*)d_in[0];
    const float* Wc = (const float*)d_in[1];
    float* out = (float*)d_out;
    digitcaps_kernel<<<dim3(1280), dim3(512), 0, stream>>>(x, Wc, out);
}

// Round 7
// 155.526 us; speedup vs baseline: 1.1048x; 1.1048x over previous
//
#include <hip/hip_runtime.h>
#include <math.h>

#define NH 10
#define NI 1152
#define NW 16
#define NS 8
#define NK 18   // i's per thread: NI / 64

// Quad-lane butterfly add via DPP quad_perm (pure VALU, no DS pipe).
// 0xB1 = perm(1,0,3,2) = xor 1 ; 0x4E = perm(2,3,0,1) = xor 2.
template<int CTRL>
__device__ __forceinline__ float dpp_add(float v) {
    union { float f; int i; } a, r;
    a.f = v;
    r.i = __builtin_amdgcn_update_dpp(a.i, a.i, CTRL, 0xF, 0xF, true);
    return v + r.f;
}

// One block = 256 threads = one (b, h). Thread (wq=tid&3, il=tid>>2) owns
// u[w][i] for w in {wq, wq+4, wq+8, wq+12}, i in {il, il+64, ..., il+1088}.
// Routing logits are linear in u (b0 = 0, agreement adds): b_i^(r) = u_i . vacc.
// Softmax over i done WITHOUT max subtraction (worst-case d ~ 44 -> e^44 ~ 1e19,
// sums <= ~1e23, all far below f32 max; ratio precision unaffected).
__global__ __launch_bounds__(256, 4)
void digitcaps_kernel(const float* __restrict__ x,
                      const float* __restrict__ Wc,
                      float* __restrict__ out)
{
    __shared__ float red3[4][NW];   // per-wave partial s_w
    __shared__ float redE[4];       // per-wave partial softmax denom
    __shared__ float vacc_sh[NW];   // accumulated v (v0 + v1)

    const int tid  = threadIdx.x;
    const int wq   = tid & 3;       // quad lane -> w = 4j + wq
    const int il   = tid >> 2;      // 0..63 -> i = 64k + il
    const int lane = tid & 63;
    const int wid  = tid >> 6;      // wave 0..3

    const int h = blockIdx.x >> 8;  // grid = 10 h * 256 b, h-major
    const int b = blockIdx.x & 255;

    const float* xb = x  + (size_t)b * (NI * NS);
    const float* Wh = Wc + (size_t)h * ((size_t)NI * NW * NS);

    float u[4][NK];   // u[j][k] = u[4j+wq][64k+il], all in registers

    #pragma unroll
    for (int k = 0; k < NK; ++k) {
        const int i = k * 64 + il;
        const float4* xp = reinterpret_cast<const float4*>(xb + (size_t)i * NS);
        const float4 x0 = xp[0], x1 = xp[1];           // broadcast across quad
        #pragma unroll
        for (int j = 0; j < 4; ++j) {
            const float4* wp = reinterpret_cast<const float4*>(
                Wh + ((size_t)i * NW + 4 * j + wq) * NS);   // quad covers 128B line
            const float4 w0 = wp[0], w1 = wp[1];
            u[j][k] = w0.x*x0.x + w0.y*x0.y + w0.z*x0.z + w0.w*x0.w
                    + w1.x*x1.x + w1.y*x1.y + w1.z*x1.z + w1.w*x1.w;
        }
    }

    for (int r = 0; r < 3; ++r) {
        float acc0 = 0.f, acc1 = 0.f, acc2 = 0.f, acc3 = 0.f, Ep = 0.f;
        if (r == 0) {
            // uniform c = 1/1152
            #pragma unroll
            for (int k = 0; k < NK; ++k) {
                acc0 += u[0][k]; acc1 += u[1][k]; acc2 += u[2][k]; acc3 += u[3][k];
            }
        } else {
            const float l2e = 1.44269504088896340736f;   // fold log2(e) into v
            const float v0 = vacc_sh[     wq] * l2e;
            const float v1 = vacc_sh[ 4 + wq] * l2e;
            const float v2 = vacc_sh[ 8 + wq] * l2e;
            const float v3 = vacc_sh[12 + wq] * l2e;
            #pragma unroll
            for (int k = 0; k < NK; ++k) {
                float p = u[0][k]*v0 + u[1][k]*v1 + u[2][k]*v2 + u[3][k]*v3;
                p = dpp_add<0xB1>(p);            // + xor1
                p = dpp_add<0x4E>(p);            // + xor2 -> all quad lanes hold d_i*log2e
                const float e = exp2f(p);
                Ep += e;                          // identical copies across quad lanes
                acc0 += e * u[0][k]; acc1 += e * u[1][k];
                acc2 += e * u[2][k]; acc3 += e * u[3][k];
            }
        }
        // reduce over il within the wave (lane bits 2..5 only; quad lanes untouched)
        #pragma unroll
        for (int s = 4; s < 64; s <<= 1) {
            acc0 += __shfl_xor(acc0, s); acc1 += __shfl_xor(acc1, s);
            acc2 += __shfl_xor(acc2, s); acc3 += __shfl_xor(acc3, s);
            Ep   += __shfl_xor(Ep, s);
        }
        if (lane < 4) {            // lane == wq, il-group 0: holds full wave sums
            red3[wid][ 0 + lane] = acc0;
            red3[wid][ 4 + lane] = acc1;
            red3[wid][ 8 + lane] = acc2;
            red3[wid][12 + lane] = acc3;
            if (lane == 0) redE[wid] = Ep;
        }
        __syncthreads();
        if (tid < NW) {            // 16 finalizer threads, w = tid
            float s = red3[0][tid] + red3[1][tid] + red3[2][tid] + red3[3][tid];
            // redE[wid] already counts each i exactly once (reduction never
            // crossed quad lanes) -> plain sum, NO extra scaling.
            const float E = (r == 0) ? (float)NI
                                     : (redE[0] + redE[1] + redE[2] + redE[3]);
            s /= E;
            float sq = s * s;
            #pragma unroll
            for (int st = 1; st < 16; st <<= 1) sq += __shfl_xor(sq, st);
            const float f = sqrtf(sq) / (1.0f + sq);   // squash: ||s|| / (1+||s||^2)
            const float v = s * f;
            if      (r == 0) vacc_sh[tid]  = v;
            else if (r == 1) vacc_sh[tid] += v;
            else out[((size_t)b * NH + h) * NW + tid] = v;
        }
        __syncthreads();
    }
}

extern "C" void kernel_launch(void* const* d_in, const int* in_sizes, int n_in,
                              void* d_out, int out_size, void* d_ws, size_t ws_size,
                              hipStream_t stream) {
    const float* x  = (const float*)d_in[0];
    const float* Wc = (const float*)d_in[1];
    float* out = (float*)d_out;
    digitcaps_kernel<<<dim3(NH * 256), dim3(256), 0, stream>>>(x, Wc, out);
}

// Round 8
// 147.347 us; speedup vs baseline: 1.1662x; 1.0555x over previous
//
#include <hip/hip_runtime.h>
#include <math.h>

#define NH 10
#define NI 1152
#define NW 16
#define NS 8
#define NK 9    // i's per thread: NI / 128

// Quad-lane butterfly add via DPP quad_perm (pure VALU, no DS pipe).
// 0xB1 = perm(1,0,3,2) = xor 1 ; 0x4E = perm(2,3,0,1) = xor 2.
template<int CTRL>
__device__ __forceinline__ float dpp_add(float v) {
    union { float f; int i; } a, r;
    a.f = v;
    r.i = __builtin_amdgcn_update_dpp(a.i, a.i, CTRL, 0xF, 0xF, true);
    return v + r.f;
}

// One block = 512 threads = one (b, h). Thread (wq=tid&3, il=tid>>2) owns
// u[w][i] for w in {wq, wq+4, wq+8, wq+12}, i in {il, il+128, ..., il+1024}.
// NK=9 keeps per-thread u at 36 regs (round-7 NK=18 cost 72 -> unified
// VGPR+AGPR ~128/thread -> only 4 waves/SIMD resident; this was the
// latency-hiding bottleneck: VALUBusy 25%, occupancy 41%).
// Routing logits are linear in u (b0 = 0): b_i^(r) = u_i . vacc.
// Softmax without max-subtraction (|d| <= ~44 -> e^44 ~ 1e19, safe in f32).
__global__ __launch_bounds__(512, 2)
void digitcaps_kernel(const float* __restrict__ x,
                      const float* __restrict__ Wc,
                      float* __restrict__ out)
{
    __shared__ float red3[8][NW];   // per-wave partial s_w
    __shared__ float redE[8];       // per-wave partial softmax denom
    __shared__ float vacc_sh[NW];   // accumulated v (v0 + v1)

    const int tid  = threadIdx.x;
    const int wq   = tid & 3;       // quad lane -> w = 4j + wq
    const int il   = tid >> 2;      // 0..127 -> i = 128k + il
    const int lane = tid & 63;
    const int wid  = tid >> 6;      // wave 0..7

    const int h = blockIdx.x >> 8;  // grid = 10 h * 256 b, h-major
    const int b = blockIdx.x & 255;

    const float* xb = x  + (size_t)b * (NI * NS);
    const float* Wh = Wc + (size_t)h * ((size_t)NI * NW * NS);

    float u[4][NK];   // u[j][k] = u[4j+wq][128k+il], all in registers

    #pragma unroll
    for (int k = 0; k < NK; ++k) {
        const int i = k * 128 + il;
        const float4* xp = reinterpret_cast<const float4*>(xb + (size_t)i * NS);
        const float4 x0 = xp[0], x1 = xp[1];           // same addr across quad -> 1 line
        #pragma unroll
        for (int j = 0; j < 4; ++j) {
            const float4* wp = reinterpret_cast<const float4*>(
                Wh + ((size_t)i * NW + 4 * j + wq) * NS);   // quad covers 128B
            const float4 w0 = wp[0], w1 = wp[1];
            u[j][k] = w0.x*x0.x + w0.y*x0.y + w0.z*x0.z + w0.w*x0.w
                    + w1.x*x1.x + w1.y*x1.y + w1.z*x1.z + w1.w*x1.w;
        }
    }

    for (int r = 0; r < 3; ++r) {
        float acc0 = 0.f, acc1 = 0.f, acc2 = 0.f, acc3 = 0.f, Ep = 0.f;
        if (r == 0) {
            // uniform c = 1/1152
            #pragma unroll
            for (int k = 0; k < NK; ++k) {
                acc0 += u[0][k]; acc1 += u[1][k]; acc2 += u[2][k]; acc3 += u[3][k];
            }
        } else {
            const float l2e = 1.44269504088896340736f;   // fold log2(e) into v
            const float v0 = vacc_sh[     wq] * l2e;
            const float v1 = vacc_sh[ 4 + wq] * l2e;
            const float v2 = vacc_sh[ 8 + wq] * l2e;
            const float v3 = vacc_sh[12 + wq] * l2e;
            #pragma unroll
            for (int k = 0; k < NK; ++k) {
                float p = u[0][k]*v0 + u[1][k]*v1 + u[2][k]*v2 + u[3][k]*v3;
                p = dpp_add<0xB1>(p);            // + xor1
                p = dpp_add<0x4E>(p);            // + xor2 -> quad holds d_i*log2e
                const float e = exp2f(p);
                Ep += e;                          // identical copies across quad lanes
                acc0 += e * u[0][k]; acc1 += e * u[1][k];
                acc2 += e * u[2][k]; acc3 += e * u[3][k];
            }
        }
        // reduce over il within the wave (lane bits 2..5 only; quad lanes untouched)
        #pragma unroll
        for (int s = 4; s < 64; s <<= 1) {
            acc0 += __shfl_xor(acc0, s); acc1 += __shfl_xor(acc1, s);
            acc2 += __shfl_xor(acc2, s); acc3 += __shfl_xor(acc3, s);
            Ep   += __shfl_xor(Ep, s);
        }
        if (lane < 4) {            // lane == wq: holds full wave sums
            red3[wid][ 0 + lane] = acc0;
            red3[wid][ 4 + lane] = acc1;
            red3[wid][ 8 + lane] = acc2;
            red3[wid][12 + lane] = acc3;
            if (lane == 0) redE[wid] = Ep;
        }
        __syncthreads();
        if (tid < NW) {            // 16 finalizer threads, w = tid
            float s = 0.f, E = 0.f;
            #pragma unroll
            for (int q = 0; q < 8; ++q) { s += red3[q][tid]; E += redE[q]; }
            if (r == 0) E = (float)NI;   // redE counts each i exactly once; no scaling
            s /= E;
            float sq = s * s;
            #pragma unroll
            for (int st = 1; st < 16; st <<= 1) sq += __shfl_xor(sq, st);
            const float f = sqrtf(sq) / (1.0f + sq);   // squash: ||s|| / (1+||s||^2)
            const float v = s * f;
            if      (r == 0) vacc_sh[tid]  = v;
            else if (r == 1) vacc_sh[tid] += v;
            else out[((size_t)b * NH + h) * NW + tid] = v;
        }
        __syncthreads();
    }
}

extern "C" void kernel_launch(void* const* d_in, const int* in_sizes, int n_in,
                              void* d_out, int out_size, void* d_ws, size_t ws_size,
                              hipStream_t stream) {
    const float* x  = (const float*)d_in[0];
    const float* Wc = (const float*)d_in[1];
    float* out = (float*)d_out;
    digitcaps_kernel<<<dim3(NH * 256), dim3(512), 0, stream>>>(x, Wc, out);
}